// Round 4
// baseline (212.815 us; speedup 1.0000x reference)
//
#include <hip/hip_runtime.h>
#include <hip/hip_bf16.h>
#include <math.h>

// Problem constants (from reference)
constexpr int   NC      = 181;        // NUM_CLASSES
constexpr int   BATCH   = 131072;
constexpr float MODC    = 6.2831853071795864769f;   // 2*pi
constexpr float HALFMOD = 3.1415926535897932385f;   // pi
constexpr float DEG2RAD = 0.017453292519943295f;    // pi/180

// magic divide by 181: exact for g < 25.87M (we need < 23.73M)
constexpr unsigned MAGIC181 = 23729102u;

// ---------------- Kernel 1: streaming label scan ----------------
// Flat int4 stream over BATCH*NC ints. N4 = 5,931,008 int4 = 2896 blocks
// x 256 threads x 8 int4. All 8 loads issued back-to-back (copy-shaped).
// Nonzero entries (exactly 4 per row) grab a slot via atomicAdd and store
// the class index as a byte. Order within a row is irrelevant (perm-min).
constexpr int K1 = 8;

__device__ __forceinline__ void deposit(unsigned g, unsigned* __restrict__ cnt,
                                        unsigned char* __restrict__ slots) {
    const unsigned row = __umulhi(g, MAGIC181);   // g / 181
    const unsigned cls = g - 181u * row;          // g % 181
    const unsigned slot = atomicAdd(&cnt[row], 1u);
    slots[row * 4u + slot] = (unsigned char)cls;
}

__global__ __launch_bounds__(256) void scan_kernel(
    const int*    __restrict__ labels,
    unsigned*     __restrict__ cnt,
    unsigned char* __restrict__ slots)
{
    const size_t base = (size_t)blockIdx.x * (256 * K1) + threadIdx.x;
    const int4* p4 = (const int4*)labels;

    int4 v[K1];
    #pragma unroll
    for (int j = 0; j < K1; ++j)
        v[j] = p4[base + (size_t)j * 256];

    #pragma unroll
    for (int j = 0; j < K1; ++j) {
        const unsigned g0 = (unsigned)(base + (size_t)j * 256) * 4u;
        if (v[j].x != 0) deposit(g0 + 0u, cnt, slots);
        if (v[j].y != 0) deposit(g0 + 1u, cnt, slots);
        if (v[j].z != 0) deposit(g0 + 2u, cnt, slots);
        if (v[j].w != 0) deposit(g0 + 3u, cnt, slots);
    }
}

// ---------------- Kernel 2: per-row perm-min + reduction ----------------
__device__ __forceinline__ float sq_mod_diff(float x) {
    // d = mod(x + pi, 2pi) - pi;  return d*d   (floored mod, matches jnp.mod)
    float t = x + HALFMOD;
    float m = t - floorf(t * (1.0f / MODC)) * MODC;
    float d = m - HALFMOD;
    return d * d;
}

__global__ __launch_bounds__(256) void finish_kernel(
    const float*         __restrict__ logits,
    const unsigned char* __restrict__ slots,
    float*               __restrict__ out)
{
    const int row = blockIdx.x * 256 + threadIdx.x;

    // 4 class indices (one byte each, coalesced uchar4)
    const uchar4 s = ((const uchar4*)slots)[row];
    // 4 doa values (rows are 724 B apart -> 4 scalar dword loads, all in flight)
    const float* lp = logits + (size_t)row * NC;
    const float doa0 = lp[0], doa1 = lp[1], doa2 = lp[2], doa3 = lp[3];

    float ang[4];
    ang[0] = ((float)s.x - 90.0f) * DEG2RAD;
    ang[1] = ((float)s.y - 90.0f) * DEG2RAD;
    ang[2] = ((float)s.z - 90.0f) * DEG2RAD;
    ang[3] = ((float)s.w - 90.0f) * DEG2RAD;

    const float doa[4] = {doa0, doa1, doa2, doa3};
    float cst[4][4];
    #pragma unroll
    for (int i = 0; i < 4; ++i)
        #pragma unroll
        for (int j = 0; j < 4; ++j)
            cst[i][j] = sq_mod_diff(doa[i] - ang[j]);

    float best = 1e30f;
    #pragma unroll
    for (int a = 0; a < 4; ++a) {
        #pragma unroll
        for (int b = 0; b < 4; ++b) {
            if (b == a) continue;
            const float top = cst[0][a] + cst[1][b];
            #pragma unroll
            for (int e = 0; e < 4; ++e) {
                if (e == a || e == b) continue;
                const int f = 6 - a - b - e;
                best = fminf(best, top + cst[2][e] + cst[3][f]);
            }
        }
    }
    float sum = sqrtf(best * 0.25f);

    // wave reduce -> block reduce -> one atomic per block
    #pragma unroll
    for (int off = 32; off > 0; off >>= 1)
        sum += __shfl_down(sum, off);

    __shared__ float wsum[4];
    const int lane = threadIdx.x & 63;
    const int wv   = threadIdx.x >> 6;
    if (lane == 0) wsum[wv] = sum;
    __syncthreads();
    if (threadIdx.x == 0) {
        float t = (wsum[0] + wsum[1]) + (wsum[2] + wsum[3]);
        atomicAdd(out, t * (1.0f / (float)BATCH));
    }
}

extern "C" void kernel_launch(void* const* d_in, const int* in_sizes, int n_in,
                              void* d_out, int out_size, void* d_ws, size_t ws_size,
                              hipStream_t stream) {
    const float* logits = (const float*)d_in[0];
    const int*   labels = (const int*)d_in[1];
    float*       out    = (float*)d_out;

    unsigned*      cnt   = (unsigned*)d_ws;                       // 512 KB
    unsigned char* slots = (unsigned char*)d_ws + (size_t)BATCH * 4; // 512 KB

    // d_out and d_ws are poisoned (0xAA) before every launch.
    hipMemsetAsync(out, 0, sizeof(float), stream);
    hipMemsetAsync(cnt, 0, (size_t)BATCH * 4, stream);
    // slots needs no init: every row receives exactly 4 deposits.

    // N4 / (256*K1) = 5,931,008 / 2048 = 2896 blocks
    scan_kernel<<<2896, 256, 0, stream>>>(labels, cnt, slots);
    finish_kernel<<<BATCH / 256, 256, 0, stream>>>(logits, slots, out);
}

// Round 5
// 197.992 us; speedup vs baseline: 1.0749x; 1.0749x over previous
//
#include <hip/hip_runtime.h>
#include <hip/hip_bf16.h>
#include <math.h>

// Problem constants (from reference)
constexpr int   NC      = 181;        // NUM_CLASSES
constexpr int   BATCH   = 131072;
constexpr float MODC    = 6.2831853071795864769f;   // 2*pi
constexpr float HALFMOD = 3.1415926535897932385f;   // pi
constexpr float DEG2RAD = 0.017453292519943295f;    // pi/180

// magic divide by 181: exact for g < 25.87M (we need < 23.73M)
constexpr unsigned MAGIC181 = 23729102u;

// ---------------- Kernel 1: streaming label scan ----------------
// Flat int4 stream over BATCH*NC ints: 2896 blocks x 256 thr x 8 int4.
// Nonzero entries set one bit in a per-row 256-bit bitmap via
// FIRE-AND-FORGET atomicOr (no return -> no vmcnt serialization).
constexpr int K1 = 8;

__device__ __forceinline__ void deposit(unsigned g, unsigned* __restrict__ bm) {
    const unsigned row = __umulhi(g, MAGIC181);   // g / 181
    const unsigned cls = g - 181u * row;          // g % 181
    atomicOr(&bm[row * 8u + (cls >> 5)], 1u << (cls & 31u));  // no return use
}

__global__ __launch_bounds__(256) void scan_kernel(
    const int*    __restrict__ labels,
    unsigned*     __restrict__ bm)
{
    const size_t base = (size_t)blockIdx.x * (256 * K1) + threadIdx.x;
    const int4* p4 = (const int4*)labels;

    int4 v[K1];
    #pragma unroll
    for (int j = 0; j < K1; ++j)
        v[j] = p4[base + (size_t)j * 256];

    #pragma unroll
    for (int j = 0; j < K1; ++j) {
        const unsigned g0 = (unsigned)(base + (size_t)j * 256) * 4u;
        if (v[j].x != 0) deposit(g0 + 0u, bm);
        if (v[j].y != 0) deposit(g0 + 1u, bm);
        if (v[j].z != 0) deposit(g0 + 2u, bm);
        if (v[j].w != 0) deposit(g0 + 3u, bm);
    }
}

// ---------------- Kernel 2: per-row perm-min + reduction ----------------
__device__ __forceinline__ float sq_mod_diff(float x) {
    // d = mod(x + pi, 2pi) - pi;  return d*d   (floored mod, matches jnp.mod)
    float t = x + HALFMOD;
    float m = t - floorf(t * (1.0f / MODC)) * MODC;
    float d = m - HALFMOD;
    return d * d;
}

__global__ __launch_bounds__(256) void finish_kernel(
    const float*    __restrict__ logits,
    const unsigned* __restrict__ bm,
    float*          __restrict__ out)
{
    const int row = blockIdx.x * 256 + threadIdx.x;

    // 256-bit row bitmap: two coalesced uint4 loads (32 B/thread)
    const uint4 w0 = ((const uint4*)bm)[(size_t)row * 2 + 0];
    const uint4 w1 = ((const uint4*)bm)[(size_t)row * 2 + 1];
    // 4 doa values (rows are 724 B apart -> 4 scalar dword loads in flight)
    const float* lp = logits + (size_t)row * NC;
    const float doa[4] = {lp[0], lp[1], lp[2], lp[3]};

    // extract the 4 set bits (exactly 4 per row)
    unsigned w[8] = {w0.x, w0.y, w0.z, w0.w, w1.x, w1.y, w1.z, w1.w};
    float ang[4];
    int found = 0;
    #pragma unroll
    for (int k = 0; k < 8; ++k) {
        unsigned mm = w[k];
        while (mm) {
            const int j = __builtin_ctz(mm);
            mm &= mm - 1;
            ang[found & 3] = ((float)(k * 32 + j) - 90.0f) * DEG2RAD;
            ++found;
        }
    }

    float cst[4][4];
    #pragma unroll
    for (int i = 0; i < 4; ++i)
        #pragma unroll
        for (int j = 0; j < 4; ++j)
            cst[i][j] = sq_mod_diff(doa[i] - ang[j]);

    float best = 1e30f;
    #pragma unroll
    for (int a = 0; a < 4; ++a) {
        #pragma unroll
        for (int b = 0; b < 4; ++b) {
            if (b == a) continue;
            const float top = cst[0][a] + cst[1][b];
            #pragma unroll
            for (int e = 0; e < 4; ++e) {
                if (e == a || e == b) continue;
                const int f = 6 - a - b - e;
                best = fminf(best, top + cst[2][e] + cst[3][f]);
            }
        }
    }
    float sum = sqrtf(best * 0.25f);

    // wave reduce -> block reduce -> one atomic per block
    #pragma unroll
    for (int off = 32; off > 0; off >>= 1)
        sum += __shfl_down(sum, off);

    __shared__ float wsum[4];
    const int lane = threadIdx.x & 63;
    const int wv   = threadIdx.x >> 6;
    if (lane == 0) wsum[wv] = sum;
    __syncthreads();
    if (threadIdx.x == 0) {
        float t = (wsum[0] + wsum[1]) + (wsum[2] + wsum[3]);
        atomicAdd(out, t * (1.0f / (float)BATCH));
    }
}

extern "C" void kernel_launch(void* const* d_in, const int* in_sizes, int n_in,
                              void* d_out, int out_size, void* d_ws, size_t ws_size,
                              hipStream_t stream) {
    const float* logits = (const float*)d_in[0];
    const int*   labels = (const int*)d_in[1];
    float*       out    = (float*)d_out;

    unsigned* bm = (unsigned*)d_ws;   // 131072 rows * 32 B = 4 MB bitmap

    // d_out and d_ws are poisoned (0xAA) before every launch.
    hipMemsetAsync(out, 0, sizeof(float), stream);
    hipMemsetAsync(bm, 0, (size_t)BATCH * 32, stream);

    // N4 / (256*K1) = 5,931,008 / 2048 = 2896 blocks
    scan_kernel<<<2896, 256, 0, stream>>>(labels, bm);
    finish_kernel<<<BATCH / 256, 256, 0, stream>>>(logits, bm, out);
}

// Round 6
// 194.082 us; speedup vs baseline: 1.0965x; 1.0201x over previous
//
#include <hip/hip_runtime.h>
#include <hip/hip_bf16.h>
#include <math.h>

// Problem constants (from reference)
constexpr int   NC      = 181;        // NUM_CLASSES
constexpr int   BATCH   = 131072;
constexpr float MODC    = 6.2831853071795864769f;   // 2*pi
constexpr float HALFMOD = 3.1415926535897932385f;   // pi
constexpr float DEG2RAD = 0.017453292519943295f;    // pi/180

// magic divide by 181: exact for g < 25.87M (we need < 23.73M)
constexpr unsigned MAGIC181 = 23729102u;

// One 1024-thread block owns 256 consecutive rows:
//   256*181 = 46336 ints = 11584 int4 (16B-aligned window), 512 blocks total.
// Deposits go to an 8 KB LDS bitmap (fire-and-forget ds_or) -> zero global
// atomics in the scan. Fused compute phase: threads 0..255 do one row each.
constexpr int RPB   = 256;                    // rows per block
constexpr int WINT4 = RPB * NC / 4;           // 11584 int4 per block
constexpr int NPT   = WINT4 / 1024;           // 11 full int4 per thread
constexpr int REM   = WINT4 - NPT * 1024;     // 320 tail int4

__device__ __forceinline__ float sq_mod_diff(float x) {
    // d = mod(x + pi, 2pi) - pi;  return d*d   (floored mod, matches jnp.mod)
    float t = x + HALFMOD;
    float m = t - floorf(t * (1.0f / MODC)) * MODC;
    float d = m - HALFMOD;
    return d * d;
}

__device__ __forceinline__ void deposit(unsigned g, unsigned rowBase,
                                        unsigned* __restrict__ bm) {
    const unsigned row  = __umulhi(g, MAGIC181);   // g / 181 (global row)
    const unsigned cls  = g - 181u * row;          // g % 181
    const unsigned lrow = row - rowBase;           // 0..255 within block
    atomicOr(&bm[lrow * 8u + (cls >> 5u)], 1u << (cls & 31u));  // LDS, no return
}

__global__ __launch_bounds__(1024) void fused_kernel(
    const float* __restrict__ logits,
    const int*   __restrict__ labels,
    float*       __restrict__ out)
{
    __shared__ unsigned bm[RPB * 8];   // 8 KB: 256 rows x 256-bit bitmap
    __shared__ float    wsum[4];

    const int tid = threadIdx.x;
    const unsigned rowBase = blockIdx.x * RPB;

    // ---- zero LDS bitmap ----
    bm[tid]        = 0u;
    bm[tid + 1024] = 0u;
    __syncthreads();

    // ---- stage this block's label window: 11 full + 1 predicated int4 ----
    const unsigned base4 = (unsigned)blockIdx.x * WINT4 + tid;
    const int4* p4 = (const int4*)labels;
    int4 v[NPT + 1];
    #pragma unroll
    for (int k = 0; k < NPT; ++k)
        v[k] = p4[(size_t)base4 + (size_t)k * 1024];
    {
        int4 t = {0, 0, 0, 0};
        if (tid < REM) t = p4[(size_t)base4 + (size_t)NPT * 1024];
        v[NPT] = t;
    }

    // ---- issue logits loads early (consumed after the barrier) ----
    float d0 = 0.f, d1 = 0.f, d2 = 0.f, d3 = 0.f;
    if (tid < RPB) {
        const float* lp = logits + (size_t)(rowBase + tid) * NC;
        d0 = lp[0]; d1 = lp[1]; d2 = lp[2]; d3 = lp[3];
    }

    // ---- scan + LDS deposit (~8.5% of int4s have any hit) ----
    #pragma unroll
    for (int k = 0; k < NPT + 1; ++k) {
        const int4 w = v[k];
        if ((w.x | w.y | w.z | w.w) != 0) {
            const unsigned g0 = (base4 + (unsigned)k * 1024u) * 4u;
            if (w.x != 0) deposit(g0 + 0u, rowBase, bm);
            if (w.y != 0) deposit(g0 + 1u, rowBase, bm);
            if (w.z != 0) deposit(g0 + 2u, rowBase, bm);
            if (w.w != 0) deposit(g0 + 3u, rowBase, bm);
        }
    }
    __syncthreads();

    // ---- compute phase: threads 0..255, one row each ----
    float sum = 0.0f;
    if (tid < RPB) {
        const float doa[4] = {d0, d1, d2, d3};

        float ang[4];
        int found = 0;
        #pragma unroll
        for (int k = 0; k < 8; ++k) {
            unsigned mm = bm[tid * 8 + k];
            while (mm) {
                const int j = __builtin_ctz(mm);
                mm &= mm - 1;
                ang[found & 3] = ((float)(k * 32 + j) - 90.0f) * DEG2RAD;
                ++found;
            }
        }

        float cst[4][4];
        #pragma unroll
        for (int i = 0; i < 4; ++i)
            #pragma unroll
            for (int j = 0; j < 4; ++j)
                cst[i][j] = sq_mod_diff(doa[i] - ang[j]);

        float best = 1e30f;
        #pragma unroll
        for (int a = 0; a < 4; ++a) {
            #pragma unroll
            for (int b = 0; b < 4; ++b) {
                if (b == a) continue;
                const float top = cst[0][a] + cst[1][b];
                #pragma unroll
                for (int e = 0; e < 4; ++e) {
                    if (e == a || e == b) continue;
                    const int f = 6 - a - b - e;
                    best = fminf(best, top + cst[2][e] + cst[3][f]);
                }
            }
        }
        sum = sqrtf(best * 0.25f);

        // wave-level reduce (threads 0..255 = waves 0..3, fully active)
        #pragma unroll
        for (int off = 32; off > 0; off >>= 1)
            sum += __shfl_down(sum, off);
        if ((tid & 63) == 0) wsum[tid >> 6] = sum;
    }
    __syncthreads();

    if (tid == 0) {
        const float t = (wsum[0] + wsum[1]) + (wsum[2] + wsum[3]);
        atomicAdd(out, t * (1.0f / (float)BATCH));   // 512 atomics total
    }
}

extern "C" void kernel_launch(void* const* d_in, const int* in_sizes, int n_in,
                              void* d_out, int out_size, void* d_ws, size_t ws_size,
                              hipStream_t stream) {
    const float* logits = (const float*)d_in[0];
    const int*   labels = (const int*)d_in[1];
    float*       out    = (float*)d_out;

    // d_out is poisoned (0xAA) before every launch — zero it first.
    hipMemsetAsync(out, 0, sizeof(float), stream);

    // BATCH / RPB = 512 blocks x 1024 threads
    fused_kernel<<<BATCH / RPB, 1024, 0, stream>>>(logits, labels, out);
}